// Round 10
// baseline (2031.194 us; speedup 1.0000x reference)
//
#include <hip/hip_runtime.h>
#include <math.h>

#define N_ROWS 10816   // 64 * 169 rows per timestep
#define T_SEQ 55
#define NPIX 169

__device__ __forceinline__ unsigned short f2bf(float f){
    unsigned u = __float_as_uint(f);
    unsigned r = u + 0x7FFFu + ((u>>16)&1u);
    return (unsigned short)(r>>16);
}
__device__ __forceinline__ float bf2f(unsigned short h){
    return __uint_as_float(((unsigned)h)<<16);
}

// Activations via v_exp_f32 + v_rcp_f32 (single-instruction 1-ulp rcp --
// IEEE div was compiling to a ~9-op div_scale/div_fmas/div_fixup sequence,
// ~720 VALU ops/thread/step across the 80 divisions; R9 VALUBusy=49%).
// NaN-safe: e->inf => rcp(inf)=0; e->0 => rcp(1)=1.
__device__ __forceinline__ float fast_rcp(float x){
    return __builtin_amdgcn_rcpf(x);
}
__device__ __forceinline__ float fast_sig(float x){
    return fast_rcp(1.0f + __expf(-x));
}
__device__ __forceinline__ float fast_tanh(float x){
    float ax = fabsf(x);
    float e  = __expf(-2.0f*ax);           // (0,1]
    float r  = (1.0f - e)*fast_rcp(1.0f + e);
    return copysignf(r, x);
}

typedef __attribute__((ext_vector_type(8))) short bfrag;
typedef __attribute__((ext_vector_type(8))) _Float16 hfrag;
typedef __attribute__((ext_vector_type(4))) float facc;

// ---------------------------------------------------------------------------
// Kernel 1: fused input transpose + 4x (1x1 conv + ReLU) chain. (unchanged)
// ---------------------------------------------------------------------------
__global__ __launch_bounds__(256) void conv1x1_chain(
    const float* __restrict__ x,
    const float* __restrict__ w0, const float* __restrict__ b0,
    const float* __restrict__ w1, const float* __restrict__ b1,
    const float* __restrict__ w2, const float* __restrict__ b2,
    const float* __restrict__ w3, const float* __restrict__ b3,
    float* __restrict__ out)
{
    int n = blockIdx.x*256 + threadIdx.x;
    int l = blockIdx.y;
    if (n >= N_ROWS) return;
    const float* xp = x + ((size_t)n*T_SEQ + l)*24;
    float in24[24];
    #pragma unroll
    for (int i=0;i<6;i++){
        float4 v = *(const float4*)(xp + 4*i);
        in24[4*i]=v.x; in24[4*i+1]=v.y; in24[4*i+2]=v.z; in24[4*i+3]=v.w;
    }
    float a[30], c[30];
    #pragma unroll
    for (int co=0;co<30;co++) a[co]=b0[co];
    #pragma unroll
    for (int ci=0;ci<24;ci++){
        float v = in24[ci];
        #pragma unroll
        for (int co=0;co<30;co++) a[co] = fmaf(v, w0[ci*30+co], a[co]);
    }
    #pragma unroll
    for (int co=0;co<30;co++) a[co] = fmaxf(a[co],0.f);

#define LAYER30(wp, bp) \
    { _Pragma("unroll") for (int co=0;co<30;co++) c[co]=(bp)[co]; \
      _Pragma("unroll") for (int ci=0;ci<30;ci++){ float v=a[ci]; \
        _Pragma("unroll") for (int co=0;co<30;co++) c[co]=fmaf(v,(wp)[ci*30+co],c[co]); } \
      _Pragma("unroll") for (int co=0;co<30;co++) a[co]=fmaxf(c[co],0.f); }

    LAYER30(w1,b1);
    LAYER30(w2,b2);
    LAYER30(w3,b3);
#undef LAYER30

    float* op = out + (size_t)l*30*N_ROWS + n;
    #pragma unroll
    for (int co=0;co<30;co++) op[(size_t)co*N_ROWS] = a[co];
}

// ---------------------------------------------------------------------------
// Kernel 2a: conv weight repack for MFMA, bf16 hi/lo. (unchanged)
// ---------------------------------------------------------------------------
__global__ __launch_bounds__(256) void repack_conv(
    const float* __restrict__ w20, const float* __restrict__ w21,
    const float* __restrict__ w22, const float* __restrict__ w23,
    unsigned short* __restrict__ cwh, unsigned short* __restrict__ cwl)
{
    int i = blockIdx.x*256 + threadIdx.x;
    if (i >= 4*25600) return;
    int layer = i / 25600, r = i - layer*25600;
    int frag = r >> 9, e = r & 511;
    int kt = frag >> 1, ct = frag & 1;
    int lane = e >> 3, j = e & 7;
    int ci = ((lane>>4)<<3) + j;
    int co = ct*16 + (lane & 15);
    const float* w = (layer==0)?w20:(layer==1)?w21:(layer==2)?w22:w23;
    float v = (ci<30 && co<30) ? w[(size_t)(kt*30 + ci)*30 + co] : 0.f;
    unsigned short h = f2bf(v);
    cwh[i] = h; cwl[i] = f2bf(v - bf2f(h));
}

// ---------------------------------------------------------------------------
// Kernel 2b: FUSED 4-layer 5x5 SAME conv + ReLU via split-bf16 MFMA.
// (unchanged from R5 -- measured win, bit-identical output)
// ---------------------------------------------------------------------------
__global__ __launch_bounds__(256, 4) void conv5x5_mfma4(
    float* __restrict__ buf,
    const unsigned short* __restrict__ cwh, const unsigned short* __restrict__ cwl,
    const float* __restrict__ bias0, const float* __restrict__ bias1,
    const float* __restrict__ bias2, const float* __restrict__ bias3)
{
    __shared__ __align__(16) unsigned short imgh[18*17*32];  // 19584 B
    __shared__ __align__(16) unsigned short imgl[18*17*32];

    int bi = blockIdx.x;
    int l = bi >> 6, b = bi & 63;
    float* ip = buf + (size_t)l*30*N_ROWS + (size_t)b*NPIX;
    const int tid = threadIdx.x;
    const int wave = tid >> 6, lane = tid & 63;
    const int m16 = lane & 15, quad = lane >> 4;

    {
        unsigned* zh = (unsigned*)imgh; unsigned* zl = (unsigned*)imgl;
        for (int i=tid; i<18*17*16; i+=256){ zh[i]=0u; zl[i]=0u; }
    }
    __syncthreads();

    for (int i=tid; i<30*NPIX; i+=256){
        int ci = i / NPIX, p = i - ci*NPIX;
        int py = p/13, px = p - py*13;
        float v = ip[(size_t)ci*N_ROWS + p];
        int L = (py+2)*17 + (px+2);
        int o = L*32 + ((((ci>>3) + L)&3)<<3) + (ci&7);
        unsigned short hh = f2bf(v);
        imgh[o] = hh; imgl[o] = f2bf(v - bf2f(hh));
    }

    int pL[3]; bool mv[3];
    #pragma unroll
    for (int mi=0; mi<3; mi++){
        int Mt = wave + mi*4;
        mv[mi] = (Mt < 11);
        int p = Mt*16 + m16;
        int py = p/13, px = p - py*13;
        pL[mi] = py*17 + px;
    }

    #pragma unroll 1
    for (int layer=0; layer<4; layer++){
        const float* bias = (layer==0)?bias0:(layer==1)?bias1:(layer==2)?bias2:bias3;
        const unsigned short* wh = cwh + (size_t)layer*25600;
        const unsigned short* wl = cwl + (size_t)layer*25600;

        __syncthreads();

        float bb[2];
        #pragma unroll
        for (int nt=0; nt<2; nt++){
            int co = nt*16 + m16;
            bb[nt] = (co < 30) ? bias[co] : 0.f;
        }
        facc acc[3][2];
        #pragma unroll
        for (int mi=0; mi<3; mi++)
            #pragma unroll
            for (int nt=0; nt<2; nt++)
                acc[mi][nt] = (facc){bb[nt], bb[nt], bb[nt], bb[nt]};

        #pragma unroll 1
        for (int kt=0; kt<25; kt++){
            int dy = kt/5, dx = kt - dy*5;
            int Ld = dy*17 + dx;
            bfrag ah[3], al[3];
            #pragma unroll
            for (int mi=0; mi<3; mi++){
                if (mv[mi]){
                    int L = pL[mi] + Ld;
                    int o = L*32 + (((quad + L)&3)<<3);
                    ah[mi] = *(const bfrag*)(imgh + o);
                    al[mi] = *(const bfrag*)(imgl + o);
                }
            }
            const unsigned short* whp = wh + (size_t)(kt*2)*512 + lane*8;
            const unsigned short* wlp = wl + (size_t)(kt*2)*512 + lane*8;
            bfrag bh0 = *(const bfrag*)(whp);
            bfrag bh1 = *(const bfrag*)(whp + 512);
            bfrag bl0 = *(const bfrag*)(wlp);
            bfrag bl1 = *(const bfrag*)(wlp + 512);
            #pragma unroll
            for (int mi=0; mi<3; mi++){
                if (mv[mi]){
                    acc[mi][0] = __builtin_amdgcn_mfma_f32_16x16x32_bf16(ah[mi], bh0, acc[mi][0],0,0,0);
                    acc[mi][1] = __builtin_amdgcn_mfma_f32_16x16x32_bf16(ah[mi], bh1, acc[mi][1],0,0,0);
                }
            }
            #pragma unroll
            for (int mi=0; mi<3; mi++){
                if (mv[mi]){
                    acc[mi][0] = __builtin_amdgcn_mfma_f32_16x16x32_bf16(al[mi], bh0, acc[mi][0],0,0,0);
                    acc[mi][1] = __builtin_amdgcn_mfma_f32_16x16x32_bf16(al[mi], bh1, acc[mi][1],0,0,0);
                }
            }
            #pragma unroll
            for (int mi=0; mi<3; mi++){
                if (mv[mi]){
                    acc[mi][0] = __builtin_amdgcn_mfma_f32_16x16x32_bf16(ah[mi], bl0, acc[mi][0],0,0,0);
                    acc[mi][1] = __builtin_amdgcn_mfma_f32_16x16x32_bf16(ah[mi], bl1, acc[mi][1],0,0,0);
                }
            }
        }

        __syncthreads();

        if (layer < 3){
            #pragma unroll
            for (int mi=0; mi<3; mi++){
                if (mv[mi]){
                    int Mt = wave + mi*4;
                    #pragma unroll
                    for (int nt=0; nt<2; nt++){
                        int co = nt*16 + m16;
                        if (co < 30){
                            #pragma unroll
                            for (int i2=0; i2<4; i2++){
                                int p = Mt*16 + quad*4 + i2;
                                if (p < NPIX){
                                    float v = fmaxf(acc[mi][nt][i2], 0.f);
                                    int py = p/13, px = p - py*13;
                                    int L = (py+2)*17 + (px+2);
                                    int o = L*32 + ((((co>>3) + L)&3)<<3) + (co&7);
                                    unsigned short hh = f2bf(v);
                                    imgh[o] = hh; imgl[o] = f2bf(v - bf2f(hh));
                                }
                            }
                        }
                    }
                }
            }
        } else {
            #pragma unroll
            for (int mi=0; mi<3; mi++){
                if (mv[mi]){
                    int Mt = wave + mi*4;
                    #pragma unroll
                    for (int nt=0; nt<2; nt++){
                        int co = nt*16 + m16;
                        if (co < 30){
                            #pragma unroll
                            for (int i2=0; i2<4; i2++){
                                int p = Mt*16 + quad*4 + i2;
                                if (p < NPIX)
                                    ip[(size_t)co*N_ROWS + p] = fmaxf(acc[mi][nt][i2], 0.f);
                            }
                        }
                    }
                }
            }
        }
    }
}

// ---------------------------------------------------------------------------
// Kernel 3: LSTM MFMA weight repack, f16 single. (unchanged from R8)
// ---------------------------------------------------------------------------
__global__ __launch_bounds__(256) void repack_mfma_f16(
    const float* __restrict__ l1w, const float* __restrict__ l1b,
    const float* __restrict__ l2w, const float* __restrict__ l2b,
    _Float16* __restrict__ bw1, _Float16* __restrict__ bw2,
    float* __restrict__ pbias1, float* __restrict__ pbias2)
{
    const int S1 = 5*32*512;   // 81920
    const int S2 = 7*32*512;   // 114688
    int i = blockIdx.x*256 + threadIdx.x;
    if (i < S1){
        int fr = i >> 9, r = i & 511;
        int kt = fr >> 5, ct = fr & 31;
        int lane = r >> 3, j = r & 7;
        int k = kt*32 + ((lane>>4)<<3) + j;
        int n = lane & 15;
        int cell = ((ct>>2)<<4) + n, g = ct & 3;
        float w = (k<130 && cell<100) ? l1w[(size_t)k*400 + g*100 + cell] : 0.f;
        bw1[i] = (_Float16)w;
    } else if (i < S1 + S2){
        int ii = i - S1;
        int fr = ii >> 9, r = ii & 511;
        int kt = fr >> 5, ct = fr & 31;
        int lane = r >> 3, j = r & 7;
        int k = kt*32 + ((lane>>4)<<3) + j;
        int n = lane & 15;
        int cell = ((ct>>2)<<4) + n, g = ct & 3;
        float w = (k<200 && cell<100) ? l2w[(size_t)k*400 + g*100 + cell] : 0.f;
        bw2[ii] = (_Float16)w;
    } else if (i < S1+S2+512){
        int col = i - S1 - S2;
        int ct = col >> 4, n = col & 15;
        int cell = ((ct>>2)<<4) + n, g = ct & 3;
        pbias1[col] = (cell<100) ? l1b[g*100+cell] : 0.f;
    } else if (i < S1+S2+1024){
        int col = i - S1 - S2 - 512;
        int ct = col >> 4, n = col & 15;
        int cell = ((ct>>2)<<4) + n, g = ct & 3;
        pbias2[col] = (cell<100) ? l2b[g*100+cell] : 0.f;
    }
}

// ---------------------------------------------------------------------------
// Kernel 4: PERSISTENT 2-layer LSTM + projection, v11.
// R9: VALU-bound (49%) at MfmaUtil 11%, VGPR down to 52. Three fixes:
//  (1) v_rcp_f32 activations (no IEEE div sequences) -- halves epilogue VALU
//  (2) wave-7 (all-padding cells) skips the entire epilogue via execz;
//      pbuf segment 7 zeroed once before the loop
//  (3) kt-loop unroll 2 retried: at 52 VGPR there is headroom the R7
//      attempt (64 VGPR, 2-term) lacked. PRE-COMMIT: FETCH>100MB => spill
//      => revert to unroll 1 keeping (1)+(2).
// ---------------------------------------------------------------------------
#define NKT1 5
#define NKT2 7
#define M_BLK 32
#define RSTR 40            // row stride in _Float16 (80 B)
#define KTSTR (32*RSTR)    // 1280 per kt-tile
__global__ __launch_bounds__(512, 4) void lstm_mfma10(
    const float* __restrict__ xall,   // [55][30][N]
    const _Float16* __restrict__ bw1, const _Float16* __restrict__ bw2,
    const float* __restrict__ pbias1, const float* __restrict__ pbias2,
    const float* __restrict__ we, const float* __restrict__ be,
    float* __restrict__ out)          // [N][55]
{
    // A matrices single f16, [kt][row(32)][k(32)+pad(8)]
    __shared__ __align__(16) _Float16 A1[NKT1*KTSTR];   // 12.8 KB
    __shared__ __align__(16) _Float16 A2[NKT2*KTSTR];   // 17.9 KB
    __shared__ float pbuf[8*M_BLK];                     // 1 KB

    const int tid  = threadIdx.x;
    const int w    = tid >> 6, lane = tid & 63;
    const int m16  = lane & 15, quad = lane >> 4;
    const int n0   = blockIdx.x * M_BLK;
    const int cell = w*16 + m16;          // wave w owns cell-tile w
    const bool cv  = (cell < 100);

    for (int i=tid; i<NKT1*KTSTR; i+=512) A1[i]=(_Float16)0.f;
    for (int i=tid; i<NKT2*KTSTR; i+=512) A2[i]=(_Float16)0.f;
    for (int i=tid; i<8*M_BLK; i+=512) pbuf[i]=0.f;   // seg 7 stays 0 forever

    float cs1[2][4] = {{0,0,0,0},{0,0,0,0}};
    float cs2[2][4] = {{0,0,0,0},{0,0,0,0}};
    float b1[4], b2[4];
    #pragma unroll
    for (int g=0; g<4; g++){
        b1[g] = pbias1[(w*4+g)*16 + m16];
        b2[g] = pbias2[(w*4+g)*16 + m16];
    }
    const float weC = cv ? we[cell] : 0.f;
    const float be0 = be[0];

    // weight fragment bases: ct = w*4+g; per kt advance 32*512 = 16384
    const _Float16* w1p = bw1 + ((size_t)(w*4)*64 + lane)*8;
    const _Float16* w2p = bw2 + ((size_t)(w*4)*64 + lane)*8;

    const int sk = tid >> 3, sq = tid & 7;   // staging role (tid<240)

    __syncthreads();   // zero-init visible

    // stage x(0): column sk (k<30), rows sq*4..sq*4+3 (kt=0 tile)
    if (tid < 240){
        float4 v = *(const float4*)(xall + (size_t)sk*N_ROWS + n0 + sq*4);
        A1[(sq*4+0)*RSTR + sk] = (_Float16)v.x;
        A1[(sq*4+1)*RSTR + sk] = (_Float16)v.y;
        A1[(sq*4+2)*RSTR + sk] = (_Float16)v.z;
        A1[(sq*4+3)*RSTR + sk] = (_Float16)v.w;
    }
    __syncthreads();

    facc acc[2][4];   // [mt][g]

// 1-term f16 GEMM; per kt: 4 W loads, 2 A ds_reads, 8 MFMA. unroll 2:
// at 52 VGPR baseline there is room for a 2-iteration scheduling window.
#define GEMM(W0, NKT, AH, BI) \
    { _Pragma("unroll") \
      for (int mt=0; mt<2; mt++) \
        _Pragma("unroll") \
        for (int g=0; g<4; g++){ float bb=(BI)[g]; acc[mt][g]=(facc){bb,bb,bb,bb}; } \
      _Pragma("unroll 2") \
      for (int kt=0; kt<(NKT); kt++){ \
        hfrag ah[2]; \
        _Pragma("unroll") \
        for (int mt=0; mt<2; mt++){ \
            int off = kt*KTSTR + (mt*16+m16)*RSTR + (quad<<3); \
            ah[mt] = *(const hfrag*)((AH) + off); } \
        const _Float16* whp = (W0) + (size_t)kt*16384; \
        hfrag wh[4]; \
        _Pragma("unroll") \
        for (int g=0; g<4; g++) wh[g] = *(const hfrag*)(whp + (size_t)g*512); \
        _Pragma("unroll") \
        for (int g=0; g<4; g++){ \
            acc[0][g]=__builtin_amdgcn_mfma_f32_16x16x32_f16(ah[0],wh[g],acc[0][g],0,0,0); \
            acc[1][g]=__builtin_amdgcn_mfma_f32_16x16x32_f16(ah[1],wh[g],acc[1][g],0,0,0); } \
      } }

    for (int t=0; t<T_SEQ; t++){
        // prefetch x(t+1); latency hidden under GEMM1
        float4 xn;
        if (t+1 < T_SEQ && tid < 240)
            xn = *(const float4*)(xall + ((size_t)(t+1)*30+sk)*N_ROWS + n0 + sq*4);

        GEMM(w1p, NKT1, A1, b1);                           // layer 1
        __syncthreads();                                   // B1

        // EPI1: h1 -> A1 (k=30+cell) and A2 (k=cell).
        // cv guards the WHOLE epilogue: wave 7 (cells>=112) takes an
        // execz branch and does zero VALU here.
        if (cv){
            #pragma unroll
            for (int mt=0; mt<2; mt++){
                #pragma unroll
                for (int i2=0;i2<4;i2++){
                    float gi = fast_sig(acc[mt][0][i2]);
                    float gj = fast_tanh(acc[mt][1][i2]);
                    float gf = fast_sig(acc[mt][2][i2] + 1.0f);
                    float go = fast_sig(acc[mt][3][i2]);
                    float cn = gf*cs1[mt][i2] + gi*gj;
                    cs1[mt][i2] = cn;
                    float h = go*fast_tanh(cn);
                    int row = mt*16 + quad*4 + i2;
                    _Float16 hh = (_Float16)h;
                    int k1 = 30 + cell;
                    A1[(k1>>5)*KTSTR + row*RSTR + (k1&31)] = hh;
                    A2[(cell>>5)*KTSTR + row*RSTR + (cell&31)] = hh;
                }
            }
        }
        // stage x(t+1) into A1 (GEMM1(t) done reading; next read after B2)
        if (t+1 < T_SEQ && tid < 240){
            A1[(sq*4+0)*RSTR + sk] = (_Float16)xn.x;
            A1[(sq*4+1)*RSTR + sk] = (_Float16)xn.y;
            A1[(sq*4+2)*RSTR + sk] = (_Float16)xn.z;
            A1[(sq*4+3)*RSTR + sk] = (_Float16)xn.w;
        }
        __syncthreads();                                   // B2

        GEMM(w2p, NKT2, A2, b2);                           // layer 2
        __syncthreads();                                   // B3

        // EPI2: h2 -> A2 (k=100+cell) + in-register projection partial.
        // Wave 7 skips everything (pbuf seg 7 pre-zeroed).
        if (w < 7){
            float pp[2][4] = {{0,0,0,0},{0,0,0,0}};
            if (cv){
                #pragma unroll
                for (int mt=0; mt<2; mt++){
                    #pragma unroll
                    for (int i2=0;i2<4;i2++){
                        float gi = fast_sig(acc[mt][0][i2]);
                        float gj = fast_tanh(acc[mt][1][i2]);
                        float gf = fast_sig(acc[mt][2][i2] + 1.0f);
                        float go = fast_sig(acc[mt][3][i2]);
                        float cn = gf*cs2[mt][i2] + gi*gj;
                        cs2[mt][i2] = cn;
                        float h = go*fast_tanh(cn);
                        pp[mt][i2] = h*weC;
                        int row = mt*16 + quad*4 + i2;
                        int k1 = 100 + cell;
                        A2[(k1>>5)*KTSTR + row*RSTR + (k1&31)] = (_Float16)h;
                    }
                }
            }
            // reduce over the 16 cells (m16 lanes) of this wave
            #pragma unroll
            for (int mt=0; mt<2; mt++){
                #pragma unroll
                for (int i2=0;i2<4;i2++){
                    float p = pp[mt][i2];
                    p += __shfl_xor(p, 1);
                    p += __shfl_xor(p, 2);
                    p += __shfl_xor(p, 4);
                    p += __shfl_xor(p, 8);
                    pp[mt][i2] = p;
                }
            }
            if (m16 == 0){
                #pragma unroll
                for (int mt=0; mt<2; mt++)
                    #pragma unroll
                    for (int i2=0;i2<4;i2++)
                        pbuf[w*M_BLK + mt*16 + quad*4 + i2] = pp[mt][i2];
            }
        }
        __syncthreads();                                   // B4

        if (tid < M_BLK){
            float s = be0;
            #pragma unroll
            for (int ww=0; ww<8; ww++) s += pbuf[ww*M_BLK + tid];
            out[(size_t)(n0+tid)*T_SEQ + t] = s;
        }
    }
#undef GEMM
}

// ---------------------------------------------------------------------------
extern "C" void kernel_launch(void* const* d_in, const int* in_sizes, int n_in,
                              void* d_out, int out_size, void* d_ws, size_t ws_size,
                              hipStream_t stream)
{
    const float* x    = (const float*)d_in[0];
    const float* w10  = (const float*)d_in[1];  const float* b10 = (const float*)d_in[2];
    const float* w11  = (const float*)d_in[3];  const float* b11 = (const float*)d_in[4];
    const float* w12  = (const float*)d_in[5];  const float* b12 = (const float*)d_in[6];
    const float* w13  = (const float*)d_in[7];  const float* b13 = (const float*)d_in[8];
    const float* w20  = (const float*)d_in[9];  const float* b20 = (const float*)d_in[10];
    const float* w21  = (const float*)d_in[11]; const float* b21 = (const float*)d_in[12];
    const float* w22  = (const float*)d_in[13]; const float* b22 = (const float*)d_in[14];
    const float* w23  = (const float*)d_in[15]; const float* b23 = (const float*)d_in[16];
    const float* l1w  = (const float*)d_in[17]; const float* l1b = (const float*)d_in[18];
    const float* l2w  = (const float*)d_in[19]; const float* l2b = (const float*)d_in[20];
    const float* we   = (const float*)d_in[21]; const float* be  = (const float*)d_in[22];
    float* out = (float*)d_out;

    // workspace layout preserved (same footprint). Conv packs overlay the
    // lstm pack region; consumed before repack_mfma_f16 (stream-serialized).
    const size_t NF = (size_t)30*N_ROWS;
    float* buf0 = (float*)d_ws;                       // [55][30][N] floats
    unsigned short* packbase = (unsigned short*)(buf0 + (size_t)T_SEQ*NF);
    _Float16* bw1 = (_Float16*)packbase;                        // 81920
    _Float16* bw2 = (_Float16*)(packbase + 2*(5*32*512));       // 114688
    float* pbias1 = (float*)(packbase + 2*(5*32*512) + 2*(7*32*512));
    float* pbias2 = pbias1 + 512;

    unsigned short* cwh = packbase;                   // 4*25600 ushorts
    unsigned short* cwl = cwh + 4*25600;              // 4*25600 ushorts

    repack_conv<<<(4*25600+255)/256, 256, 0, stream>>>(w20, w21, w22, w23, cwh, cwl);

    dim3 g1((N_ROWS+255)/256, T_SEQ);
    conv1x1_chain<<<g1, 256, 0, stream>>>(x, w10,b10, w11,b11, w12,b12, w13,b13, buf0);

    conv5x5_mfma4<<<T_SEQ*64, 256, 0, stream>>>(buf0, cwh, cwl, b20, b21, b22, b23);

    const int REPACK_N = 5*32*512 + 7*32*512 + 1024;
    repack_mfma_f16<<<(REPACK_N+255)/256, 256, 0, stream>>>(
        l1w, l1b, l2w, l2b, bw1, bw2, pbias1, pbias2);

    lstm_mfma10<<<N_ROWS/M_BLK, 512, 0, stream>>>(buf0, bw1, bw2,
                                                  pbias1, pbias2, we, be, out);
}

// Round 11
// 1025.175 us; speedup vs baseline: 1.9813x; 1.9813x over previous
//
#include <hip/hip_runtime.h>
#include <math.h>

#define N_ROWS 10816   // 64 * 169 rows per timestep
#define T_SEQ 55
#define NPIX 169

__device__ __forceinline__ unsigned short f2bf(float f){
    unsigned u = __float_as_uint(f);
    unsigned r = u + 0x7FFFu + ((u>>16)&1u);
    return (unsigned short)(r>>16);
}
__device__ __forceinline__ float bf2f(unsigned short h){
    return __uint_as_float(((unsigned)h)<<16);
}

// Activations via v_exp_f32 + v_rcp_f32 (single-instruction 1-ulp rcp).
// NaN-safe: e->inf => rcp(inf)=0; e->0 => rcp(1)=1.
__device__ __forceinline__ float fast_rcp(float x){
    return __builtin_amdgcn_rcpf(x);
}
__device__ __forceinline__ float fast_sig(float x){
    return fast_rcp(1.0f + __expf(-x));
}
__device__ __forceinline__ float fast_tanh(float x){
    float ax = fabsf(x);
    float e  = __expf(-2.0f*ax);           // (0,1]
    float r  = (1.0f - e)*fast_rcp(1.0f + e);
    return copysignf(r, x);
}

typedef __attribute__((ext_vector_type(8))) short bfrag;
typedef __attribute__((ext_vector_type(8))) _Float16 hfrag;
typedef __attribute__((ext_vector_type(4))) float facc;

// ---------------------------------------------------------------------------
// Kernel 1: fused input transpose + 4x (1x1 conv + ReLU) chain. (unchanged)
// ---------------------------------------------------------------------------
__global__ __launch_bounds__(256) void conv1x1_chain(
    const float* __restrict__ x,
    const float* __restrict__ w0, const float* __restrict__ b0,
    const float* __restrict__ w1, const float* __restrict__ b1,
    const float* __restrict__ w2, const float* __restrict__ b2,
    const float* __restrict__ w3, const float* __restrict__ b3,
    float* __restrict__ out)
{
    int n = blockIdx.x*256 + threadIdx.x;
    int l = blockIdx.y;
    if (n >= N_ROWS) return;
    const float* xp = x + ((size_t)n*T_SEQ + l)*24;
    float in24[24];
    #pragma unroll
    for (int i=0;i<6;i++){
        float4 v = *(const float4*)(xp + 4*i);
        in24[4*i]=v.x; in24[4*i+1]=v.y; in24[4*i+2]=v.z; in24[4*i+3]=v.w;
    }
    float a[30], c[30];
    #pragma unroll
    for (int co=0;co<30;co++) a[co]=b0[co];
    #pragma unroll
    for (int ci=0;ci<24;ci++){
        float v = in24[ci];
        #pragma unroll
        for (int co=0;co<30;co++) a[co] = fmaf(v, w0[ci*30+co], a[co]);
    }
    #pragma unroll
    for (int co=0;co<30;co++) a[co] = fmaxf(a[co],0.f);

#define LAYER30(wp, bp) \
    { _Pragma("unroll") for (int co=0;co<30;co++) c[co]=(bp)[co]; \
      _Pragma("unroll") for (int ci=0;ci<30;ci++){ float v=a[ci]; \
        _Pragma("unroll") for (int co=0;co<30;co++) c[co]=fmaf(v,(wp)[ci*30+co],c[co]); } \
      _Pragma("unroll") for (int co=0;co<30;co++) a[co]=fmaxf(c[co],0.f); }

    LAYER30(w1,b1);
    LAYER30(w2,b2);
    LAYER30(w3,b3);
#undef LAYER30

    float* op = out + (size_t)l*30*N_ROWS + n;
    #pragma unroll
    for (int co=0;co<30;co++) op[(size_t)co*N_ROWS] = a[co];
}

// ---------------------------------------------------------------------------
// Kernel 2a: conv weight repack for MFMA, bf16 hi/lo. (unchanged)
// ---------------------------------------------------------------------------
__global__ __launch_bounds__(256) void repack_conv(
    const float* __restrict__ w20, const float* __restrict__ w21,
    const float* __restrict__ w22, const float* __restrict__ w23,
    unsigned short* __restrict__ cwh, unsigned short* __restrict__ cwl)
{
    int i = blockIdx.x*256 + threadIdx.x;
    if (i >= 4*25600) return;
    int layer = i / 25600, r = i - layer*25600;
    int frag = r >> 9, e = r & 511;
    int kt = frag >> 1, ct = frag & 1;
    int lane = e >> 3, j = e & 7;
    int ci = ((lane>>4)<<3) + j;
    int co = ct*16 + (lane & 15);
    const float* w = (layer==0)?w20:(layer==1)?w21:(layer==2)?w22:w23;
    float v = (ci<30 && co<30) ? w[(size_t)(kt*30 + ci)*30 + co] : 0.f;
    unsigned short h = f2bf(v);
    cwh[i] = h; cwl[i] = f2bf(v - bf2f(h));
}

// ---------------------------------------------------------------------------
// Kernel 2b: FUSED 4-layer 5x5 SAME conv + ReLU via split-bf16 MFMA.
// (unchanged from R5 -- measured win, bit-identical output)
// ---------------------------------------------------------------------------
__global__ __launch_bounds__(256, 4) void conv5x5_mfma4(
    float* __restrict__ buf,
    const unsigned short* __restrict__ cwh, const unsigned short* __restrict__ cwl,
    const float* __restrict__ bias0, const float* __restrict__ bias1,
    const float* __restrict__ bias2, const float* __restrict__ bias3)
{
    __shared__ __align__(16) unsigned short imgh[18*17*32];  // 19584 B
    __shared__ __align__(16) unsigned short imgl[18*17*32];

    int bi = blockIdx.x;
    int l = bi >> 6, b = bi & 63;
    float* ip = buf + (size_t)l*30*N_ROWS + (size_t)b*NPIX;
    const int tid = threadIdx.x;
    const int wave = tid >> 6, lane = tid & 63;
    const int m16 = lane & 15, quad = lane >> 4;

    {
        unsigned* zh = (unsigned*)imgh; unsigned* zl = (unsigned*)imgl;
        for (int i=tid; i<18*17*16; i+=256){ zh[i]=0u; zl[i]=0u; }
    }
    __syncthreads();

    for (int i=tid; i<30*NPIX; i+=256){
        int ci = i / NPIX, p = i - ci*NPIX;
        int py = p/13, px = p - py*13;
        float v = ip[(size_t)ci*N_ROWS + p];
        int L = (py+2)*17 + (px+2);
        int o = L*32 + ((((ci>>3) + L)&3)<<3) + (ci&7);
        unsigned short hh = f2bf(v);
        imgh[o] = hh; imgl[o] = f2bf(v - bf2f(hh));
    }

    int pL[3]; bool mv[3];
    #pragma unroll
    for (int mi=0; mi<3; mi++){
        int Mt = wave + mi*4;
        mv[mi] = (Mt < 11);
        int p = Mt*16 + m16;
        int py = p/13, px = p - py*13;
        pL[mi] = py*17 + px;
    }

    #pragma unroll 1
    for (int layer=0; layer<4; layer++){
        const float* bias = (layer==0)?bias0:(layer==1)?bias1:(layer==2)?bias2:bias3;
        const unsigned short* wh = cwh + (size_t)layer*25600;
        const unsigned short* wl = cwl + (size_t)layer*25600;

        __syncthreads();

        float bb[2];
        #pragma unroll
        for (int nt=0; nt<2; nt++){
            int co = nt*16 + m16;
            bb[nt] = (co < 30) ? bias[co] : 0.f;
        }
        facc acc[3][2];
        #pragma unroll
        for (int mi=0; mi<3; mi++)
            #pragma unroll
            for (int nt=0; nt<2; nt++)
                acc[mi][nt] = (facc){bb[nt], bb[nt], bb[nt], bb[nt]};

        #pragma unroll 1
        for (int kt=0; kt<25; kt++){
            int dy = kt/5, dx = kt - dy*5;
            int Ld = dy*17 + dx;
            bfrag ah[3], al[3];
            #pragma unroll
            for (int mi=0; mi<3; mi++){
                if (mv[mi]){
                    int L = pL[mi] + Ld;
                    int o = L*32 + (((quad + L)&3)<<3);
                    ah[mi] = *(const bfrag*)(imgh + o);
                    al[mi] = *(const bfrag*)(imgl + o);
                }
            }
            const unsigned short* whp = wh + (size_t)(kt*2)*512 + lane*8;
            const unsigned short* wlp = wl + (size_t)(kt*2)*512 + lane*8;
            bfrag bh0 = *(const bfrag*)(whp);
            bfrag bh1 = *(const bfrag*)(whp + 512);
            bfrag bl0 = *(const bfrag*)(wlp);
            bfrag bl1 = *(const bfrag*)(wlp + 512);
            #pragma unroll
            for (int mi=0; mi<3; mi++){
                if (mv[mi]){
                    acc[mi][0] = __builtin_amdgcn_mfma_f32_16x16x32_bf16(ah[mi], bh0, acc[mi][0],0,0,0);
                    acc[mi][1] = __builtin_amdgcn_mfma_f32_16x16x32_bf16(ah[mi], bh1, acc[mi][1],0,0,0);
                }
            }
            #pragma unroll
            for (int mi=0; mi<3; mi++){
                if (mv[mi]){
                    acc[mi][0] = __builtin_amdgcn_mfma_f32_16x16x32_bf16(al[mi], bh0, acc[mi][0],0,0,0);
                    acc[mi][1] = __builtin_amdgcn_mfma_f32_16x16x32_bf16(al[mi], bh1, acc[mi][1],0,0,0);
                }
            }
            #pragma unroll
            for (int mi=0; mi<3; mi++){
                if (mv[mi]){
                    acc[mi][0] = __builtin_amdgcn_mfma_f32_16x16x32_bf16(ah[mi], bl0, acc[mi][0],0,0,0);
                    acc[mi][1] = __builtin_amdgcn_mfma_f32_16x16x32_bf16(ah[mi], bl1, acc[mi][1],0,0,0);
                }
            }
        }

        __syncthreads();

        if (layer < 3){
            #pragma unroll
            for (int mi=0; mi<3; mi++){
                if (mv[mi]){
                    int Mt = wave + mi*4;
                    #pragma unroll
                    for (int nt=0; nt<2; nt++){
                        int co = nt*16 + m16;
                        if (co < 30){
                            #pragma unroll
                            for (int i2=0; i2<4; i2++){
                                int p = Mt*16 + quad*4 + i2;
                                if (p < NPIX){
                                    float v = fmaxf(acc[mi][nt][i2], 0.f);
                                    int py = p/13, px = p - py*13;
                                    int L = (py+2)*17 + (px+2);
                                    int o = L*32 + ((((co>>3) + L)&3)<<3) + (co&7);
                                    unsigned short hh = f2bf(v);
                                    imgh[o] = hh; imgl[o] = f2bf(v - bf2f(hh));
                                }
                            }
                        }
                    }
                }
            }
        } else {
            #pragma unroll
            for (int mi=0; mi<3; mi++){
                if (mv[mi]){
                    int Mt = wave + mi*4;
                    #pragma unroll
                    for (int nt=0; nt<2; nt++){
                        int co = nt*16 + m16;
                        if (co < 30){
                            #pragma unroll
                            for (int i2=0; i2<4; i2++){
                                int p = Mt*16 + quad*4 + i2;
                                if (p < NPIX)
                                    ip[(size_t)co*N_ROWS + p] = fmaxf(acc[mi][nt][i2], 0.f);
                            }
                        }
                    }
                }
            }
        }
    }
}

// ---------------------------------------------------------------------------
// Kernel 3: LSTM MFMA weight repack, f16 single. (unchanged from R8)
// ---------------------------------------------------------------------------
__global__ __launch_bounds__(256) void repack_mfma_f16(
    const float* __restrict__ l1w, const float* __restrict__ l1b,
    const float* __restrict__ l2w, const float* __restrict__ l2b,
    _Float16* __restrict__ bw1, _Float16* __restrict__ bw2,
    float* __restrict__ pbias1, float* __restrict__ pbias2)
{
    const int S1 = 5*32*512;   // 81920
    const int S2 = 7*32*512;   // 114688
    int i = blockIdx.x*256 + threadIdx.x;
    if (i < S1){
        int fr = i >> 9, r = i & 511;
        int kt = fr >> 5, ct = fr & 31;
        int lane = r >> 3, j = r & 7;
        int k = kt*32 + ((lane>>4)<<3) + j;
        int n = lane & 15;
        int cell = ((ct>>2)<<4) + n, g = ct & 3;
        float w = (k<130 && cell<100) ? l1w[(size_t)k*400 + g*100 + cell] : 0.f;
        bw1[i] = (_Float16)w;
    } else if (i < S1 + S2){
        int ii = i - S1;
        int fr = ii >> 9, r = ii & 511;
        int kt = fr >> 5, ct = fr & 31;
        int lane = r >> 3, j = r & 7;
        int k = kt*32 + ((lane>>4)<<3) + j;
        int n = lane & 15;
        int cell = ((ct>>2)<<4) + n, g = ct & 3;
        float w = (k<200 && cell<100) ? l2w[(size_t)k*400 + g*100 + cell] : 0.f;
        bw2[ii] = (_Float16)w;
    } else if (i < S1+S2+512){
        int col = i - S1 - S2;
        int ct = col >> 4, n = col & 15;
        int cell = ((ct>>2)<<4) + n, g = ct & 3;
        pbias1[col] = (cell<100) ? l1b[g*100+cell] : 0.f;
    } else if (i < S1+S2+1024){
        int col = i - S1 - S2 - 512;
        int ct = col >> 4, n = col & 15;
        int cell = ((ct>>2)<<4) + n, g = ct & 3;
        pbias2[col] = (cell<100) ? l2b[g*100+cell] : 0.f;
    }
}

// ---------------------------------------------------------------------------
// Kernel 4: PERSISTENT 2-layer LSTM + projection, v12.
// R10 postmortem: unroll 2 spilled AGAIN (FETCH 3.5GB) -- 3rd confirmation
// that widening the kt scheduling window at source level spills on this
// structure. Knob retired permanently. This version = R9's proven unroll-1
// loop + the two untested VALU cuts from R10:
//  (1) v_rcp_f32 activations (kills the ~9-op IEEE div sequences; 80
//      divs/thread/step were the largest VALU term at R9's VALUBusy=49%)
//  (2) wave-7 (all-padding cells) skips both epilogues via execz;
//      pbuf segment 7 zeroed once before the loop.
// ---------------------------------------------------------------------------
#define NKT1 5
#define NKT2 7
#define M_BLK 32
#define RSTR 40            // row stride in _Float16 (80 B)
#define KTSTR (32*RSTR)    // 1280 per kt-tile
__global__ __launch_bounds__(512, 4) void lstm_mfma11(
    const float* __restrict__ xall,   // [55][30][N]
    const _Float16* __restrict__ bw1, const _Float16* __restrict__ bw2,
    const float* __restrict__ pbias1, const float* __restrict__ pbias2,
    const float* __restrict__ we, const float* __restrict__ be,
    float* __restrict__ out)          // [N][55]
{
    // A matrices single f16, [kt][row(32)][k(32)+pad(8)]
    __shared__ __align__(16) _Float16 A1[NKT1*KTSTR];   // 12.8 KB
    __shared__ __align__(16) _Float16 A2[NKT2*KTSTR];   // 17.9 KB
    __shared__ float pbuf[8*M_BLK];                     // 1 KB

    const int tid  = threadIdx.x;
    const int w    = tid >> 6, lane = tid & 63;
    const int m16  = lane & 15, quad = lane >> 4;
    const int n0   = blockIdx.x * M_BLK;
    const int cell = w*16 + m16;          // wave w owns cell-tile w
    const bool cv  = (cell < 100);

    for (int i=tid; i<NKT1*KTSTR; i+=512) A1[i]=(_Float16)0.f;
    for (int i=tid; i<NKT2*KTSTR; i+=512) A2[i]=(_Float16)0.f;
    for (int i=tid; i<8*M_BLK; i+=512) pbuf[i]=0.f;   // seg 7 stays 0 forever

    float cs1[2][4] = {{0,0,0,0},{0,0,0,0}};
    float cs2[2][4] = {{0,0,0,0},{0,0,0,0}};
    float b1[4], b2[4];
    #pragma unroll
    for (int g=0; g<4; g++){
        b1[g] = pbias1[(w*4+g)*16 + m16];
        b2[g] = pbias2[(w*4+g)*16 + m16];
    }
    const float weC = cv ? we[cell] : 0.f;
    const float be0 = be[0];

    // weight fragment bases: ct = w*4+g; per kt advance 32*512 = 16384
    const _Float16* w1p = bw1 + ((size_t)(w*4)*64 + lane)*8;
    const _Float16* w2p = bw2 + ((size_t)(w*4)*64 + lane)*8;

    const int sk = tid >> 3, sq = tid & 7;   // staging role (tid<240)

    __syncthreads();   // zero-init visible

    // stage x(0): column sk (k<30), rows sq*4..sq*4+3 (kt=0 tile)
    if (tid < 240){
        float4 v = *(const float4*)(xall + (size_t)sk*N_ROWS + n0 + sq*4);
        A1[(sq*4+0)*RSTR + sk] = (_Float16)v.x;
        A1[(sq*4+1)*RSTR + sk] = (_Float16)v.y;
        A1[(sq*4+2)*RSTR + sk] = (_Float16)v.z;
        A1[(sq*4+3)*RSTR + sk] = (_Float16)v.w;
    }
    __syncthreads();

    facc acc[2][4];   // [mt][g]

// 1-term f16 GEMM; per kt: 4 W loads, 2 A ds_reads, 8 MFMA. unroll 1 --
// FINAL (unroll 2 spilled at R7 and R10; knob retired).
#define GEMM(W0, NKT, AH, BI) \
    { _Pragma("unroll") \
      for (int mt=0; mt<2; mt++) \
        _Pragma("unroll") \
        for (int g=0; g<4; g++){ float bb=(BI)[g]; acc[mt][g]=(facc){bb,bb,bb,bb}; } \
      _Pragma("unroll 1") \
      for (int kt=0; kt<(NKT); kt++){ \
        hfrag ah[2]; \
        _Pragma("unroll") \
        for (int mt=0; mt<2; mt++){ \
            int off = kt*KTSTR + (mt*16+m16)*RSTR + (quad<<3); \
            ah[mt] = *(const hfrag*)((AH) + off); } \
        const _Float16* whp = (W0) + (size_t)kt*16384; \
        hfrag wh[4]; \
        _Pragma("unroll") \
        for (int g=0; g<4; g++) wh[g] = *(const hfrag*)(whp + (size_t)g*512); \
        _Pragma("unroll") \
        for (int g=0; g<4; g++){ \
            acc[0][g]=__builtin_amdgcn_mfma_f32_16x16x32_f16(ah[0],wh[g],acc[0][g],0,0,0); \
            acc[1][g]=__builtin_amdgcn_mfma_f32_16x16x32_f16(ah[1],wh[g],acc[1][g],0,0,0); } \
      } }

    for (int t=0; t<T_SEQ; t++){
        // prefetch x(t+1); latency hidden under GEMM1
        float4 xn;
        if (t+1 < T_SEQ && tid < 240)
            xn = *(const float4*)(xall + ((size_t)(t+1)*30+sk)*N_ROWS + n0 + sq*4);

        GEMM(w1p, NKT1, A1, b1);                           // layer 1
        __syncthreads();                                   // B1

        // EPI1: h1 -> A1 (k=30+cell) and A2 (k=cell).
        // cv guards the WHOLE epilogue: wave 7 takes execz, zero VALU.
        if (cv){
            #pragma unroll
            for (int mt=0; mt<2; mt++){
                #pragma unroll
                for (int i2=0;i2<4;i2++){
                    float gi = fast_sig(acc[mt][0][i2]);
                    float gj = fast_tanh(acc[mt][1][i2]);
                    float gf = fast_sig(acc[mt][2][i2] + 1.0f);
                    float go = fast_sig(acc[mt][3][i2]);
                    float cn = gf*cs1[mt][i2] + gi*gj;
                    cs1[mt][i2] = cn;
                    float h = go*fast_tanh(cn);
                    int row = mt*16 + quad*4 + i2;
                    _Float16 hh = (_Float16)h;
                    int k1 = 30 + cell;
                    A1[(k1>>5)*KTSTR + row*RSTR + (k1&31)] = hh;
                    A2[(cell>>5)*KTSTR + row*RSTR + (cell&31)] = hh;
                }
            }
        }
        // stage x(t+1) into A1 (GEMM1(t) done reading; next read after B2)
        if (t+1 < T_SEQ && tid < 240){
            A1[(sq*4+0)*RSTR + sk] = (_Float16)xn.x;
            A1[(sq*4+1)*RSTR + sk] = (_Float16)xn.y;
            A1[(sq*4+2)*RSTR + sk] = (_Float16)xn.z;
            A1[(sq*4+3)*RSTR + sk] = (_Float16)xn.w;
        }
        __syncthreads();                                   // B2

        GEMM(w2p, NKT2, A2, b2);                           // layer 2
        __syncthreads();                                   // B3

        // EPI2: h2 -> A2 (k=100+cell) + in-register projection partial.
        // Wave 7 skips everything (pbuf seg 7 pre-zeroed).
        if (w < 7){
            float pp[2][4] = {{0,0,0,0},{0,0,0,0}};
            if (cv){
                #pragma unroll
                for (int mt=0; mt<2; mt++){
                    #pragma unroll
                    for (int i2=0;i2<4;i2++){
                        float gi = fast_sig(acc[mt][0][i2]);
                        float gj = fast_tanh(acc[mt][1][i2]);
                        float gf = fast_sig(acc[mt][2][i2] + 1.0f);
                        float go = fast_sig(acc[mt][3][i2]);
                        float cn = gf*cs2[mt][i2] + gi*gj;
                        cs2[mt][i2] = cn;
                        float h = go*fast_tanh(cn);
                        pp[mt][i2] = h*weC;
                        int row = mt*16 + quad*4 + i2;
                        int k1 = 100 + cell;
                        A2[(k1>>5)*KTSTR + row*RSTR + (k1&31)] = (_Float16)h;
                    }
                }
            }
            // reduce over the 16 cells (m16 lanes) of this wave
            #pragma unroll
            for (int mt=0; mt<2; mt++){
                #pragma unroll
                for (int i2=0;i2<4;i2++){
                    float p = pp[mt][i2];
                    p += __shfl_xor(p, 1);
                    p += __shfl_xor(p, 2);
                    p += __shfl_xor(p, 4);
                    p += __shfl_xor(p, 8);
                    pp[mt][i2] = p;
                }
            }
            if (m16 == 0){
                #pragma unroll
                for (int mt=0; mt<2; mt++)
                    #pragma unroll
                    for (int i2=0;i2<4;i2++)
                        pbuf[w*M_BLK + mt*16 + quad*4 + i2] = pp[mt][i2];
            }
        }
        __syncthreads();                                   // B4

        if (tid < M_BLK){
            float s = be0;
            #pragma unroll
            for (int ww=0; ww<8; ww++) s += pbuf[ww*M_BLK + tid];
            out[(size_t)(n0+tid)*T_SEQ + t] = s;
        }
    }
#undef GEMM
}

// ---------------------------------------------------------------------------
extern "C" void kernel_launch(void* const* d_in, const int* in_sizes, int n_in,
                              void* d_out, int out_size, void* d_ws, size_t ws_size,
                              hipStream_t stream)
{
    const float* x    = (const float*)d_in[0];
    const float* w10  = (const float*)d_in[1];  const float* b10 = (const float*)d_in[2];
    const float* w11  = (const float*)d_in[3];  const float* b11 = (const float*)d_in[4];
    const float* w12  = (const float*)d_in[5];  const float* b12 = (const float*)d_in[6];
    const float* w13  = (const float*)d_in[7];  const float* b13 = (const float*)d_in[8];
    const float* w20  = (const float*)d_in[9];  const float* b20 = (const float*)d_in[10];
    const float* w21  = (const float*)d_in[11]; const float* b21 = (const float*)d_in[12];
    const float* w22  = (const float*)d_in[13]; const float* b22 = (const float*)d_in[14];
    const float* w23  = (const float*)d_in[15]; const float* b23 = (const float*)d_in[16];
    const float* l1w  = (const float*)d_in[17]; const float* l1b = (const float*)d_in[18];
    const float* l2w  = (const float*)d_in[19]; const float* l2b = (const float*)d_in[20];
    const float* we   = (const float*)d_in[21]; const float* be  = (const float*)d_in[22];
    float* out = (float*)d_out;

    // workspace layout preserved (same footprint). Conv packs overlay the
    // lstm pack region; consumed before repack_mfma_f16 (stream-serialized).
    const size_t NF = (size_t)30*N_ROWS;
    float* buf0 = (float*)d_ws;                       // [55][30][N] floats
    unsigned short* packbase = (unsigned short*)(buf0 + (size_t)T_SEQ*NF);
    _Float16* bw1 = (_Float16*)packbase;                        // 81920
    _Float16* bw2 = (_Float16*)(packbase + 2*(5*32*512));       // 114688
    float* pbias1 = (float*)(packbase + 2*(5*32*512) + 2*(7*32*512));
    float* pbias2 = pbias1 + 512;

    unsigned short* cwh = packbase;                   // 4*25600 ushorts
    unsigned short* cwl = cwh + 4*25600;              // 4*25600 ushorts

    repack_conv<<<(4*25600+255)/256, 256, 0, stream>>>(w20, w21, w22, w23, cwh, cwl);

    dim3 g1((N_ROWS+255)/256, T_SEQ);
    conv1x1_chain<<<g1, 256, 0, stream>>>(x, w10,b10, w11,b11, w12,b12, w13,b13, buf0);

    conv5x5_mfma4<<<T_SEQ*64, 256, 0, stream>>>(buf0, cwh, cwl, b20, b21, b22, b23);

    const int REPACK_N = 5*32*512 + 7*32*512 + 1024;
    repack_mfma_f16<<<(REPACK_N+255)/256, 256, 0, stream>>>(
        l1w, l1b, l2w, l2b, bw1, bw2, pbias1, pbias2);

    lstm_mfma11<<<N_ROWS/M_BLK, 512, 0, stream>>>(buf0, bw1, bw2,
                                                  pbias1, pbias2, we, be, out);
}

// Round 12
// 886.923 us; speedup vs baseline: 2.2902x; 1.1559x over previous
//
#include <hip/hip_runtime.h>
#include <math.h>

#define N_ROWS 10816   // 64 * 169 rows per timestep
#define T_SEQ 55
#define NPIX 169

// Activations via v_exp_f32 + v_rcp_f32 (single-instruction 1-ulp rcp).
// NaN-safe: e->inf => rcp(inf)=0; e->0 => rcp(1)=1.
__device__ __forceinline__ float fast_rcp(float x){
    return __builtin_amdgcn_rcpf(x);
}
__device__ __forceinline__ float fast_sig(float x){
    return fast_rcp(1.0f + __expf(-x));
}
__device__ __forceinline__ float fast_tanh(float x){
    float ax = fabsf(x);
    float e  = __expf(-2.0f*ax);           // (0,1]
    float r  = (1.0f - e)*fast_rcp(1.0f + e);
    return copysignf(r, x);
}

typedef __attribute__((ext_vector_type(8))) _Float16 hfrag;
typedef __attribute__((ext_vector_type(4))) float facc;

// ---------------------------------------------------------------------------
// Kernel 1: conv weight repack for MFMA, f16 single (R12: was bf16 hi/lo).
// Layout per layer: 25 kt (one 5x5 tap, ci padded 30->32) x 2 col-tiles x
// [lane(64)][8]: k = ((lane>>4)<<3)+j (=ci), col = ct*16 + (lane&15).
// ---------------------------------------------------------------------------
__global__ __launch_bounds__(256) void repack_conv_f16(
    const float* __restrict__ w20, const float* __restrict__ w21,
    const float* __restrict__ w22, const float* __restrict__ w23,
    _Float16* __restrict__ cw)
{
    int i = blockIdx.x*256 + threadIdx.x;
    if (i >= 4*25600) return;
    int layer = i / 25600, r = i - layer*25600;
    int frag = r >> 9, e = r & 511;
    int kt = frag >> 1, ct = frag & 1;
    int lane = e >> 3, j = e & 7;
    int ci = ((lane>>4)<<3) + j;
    int co = ct*16 + (lane & 15);
    const float* w = (layer==0)?w20:(layer==1)?w21:(layer==2)?w22:w23;
    float v = (ci<30 && co<30) ? w[(size_t)(kt*30 + ci)*30 + co] : 0.f;
    cw[i] = (_Float16)v;
}

// ---------------------------------------------------------------------------
// Kernel 2: FULLY-FUSED conv stack (R12):
//   1x1 chain (4 layers, per-pixel VALU, registers) -> LDS f16 image ->
//   4x (5x5 SAME conv + ReLU) via 1-term f16 MFMA -> buf0 for the LSTM.
// vs R11: (a) conv5x5 3-term bf16 -> 1-term f16 (MFMA/wave 1800->600; LDS
// 39->19.6 KB; justified by R8-R11 evidence: absmax pinned at 1 ulp through
// pure-f16 LSTM), (b) conv1x1 kernel fused in as a register prologue --
// kills its dispatch + the 142 MB buf0 write+read between the two kernels.
// PRE-COMMIT: if passed=false, revert convs to the R5 bf16-3-term pair.
// ---------------------------------------------------------------------------
__global__ __launch_bounds__(256, 4) void conv_fused(
    const float* __restrict__ x,
    const float* __restrict__ w0, const float* __restrict__ b0,
    const float* __restrict__ w1, const float* __restrict__ b1,
    const float* __restrict__ w2, const float* __restrict__ b2,
    const float* __restrict__ w3, const float* __restrict__ b3,
    const _Float16* __restrict__ cw,
    const float* __restrict__ cb0, const float* __restrict__ cb1,
    const float* __restrict__ cb2, const float* __restrict__ cb3,
    float* __restrict__ buf)
{
    __shared__ __align__(16) _Float16 img[18*17*32];   // 19584 B, f16 single

    int bi = blockIdx.x;
    int l = bi >> 6, b = bi & 63;
    float* ip = buf + (size_t)l*30*N_ROWS + (size_t)b*NPIX;
    const int tid = threadIdx.x;
    const int wave = tid >> 6, lane = tid & 63;
    const int m16 = lane & 15, quad = lane >> 4;

    // zero-init img (halo + ci 30/31 stay zero forever)
    for (int i=tid; i<18*17*16; i+=256) ((unsigned*)img)[i] = 0u;
    __syncthreads();

    // ---- Phase 0: per-pixel 1x1 conv chain (registers) -> img f16 ----
    if (tid < NPIX){
        const float* xp = x + ((size_t)(b*NPIX + tid)*T_SEQ + l)*24;
        float in24[24];
        #pragma unroll
        for (int i=0;i<6;i++){
            float4 v = *(const float4*)(xp + 4*i);
            in24[4*i]=v.x; in24[4*i+1]=v.y; in24[4*i+2]=v.z; in24[4*i+3]=v.w;
        }
        float a[30], c[30];
        #pragma unroll
        for (int co=0;co<30;co++) a[co]=b0[co];
        #pragma unroll
        for (int ci=0;ci<24;ci++){
            float v = in24[ci];
            #pragma unroll
            for (int co=0;co<30;co++) a[co] = fmaf(v, w0[ci*30+co], a[co]);
        }
        #pragma unroll
        for (int co=0;co<30;co++) a[co] = fmaxf(a[co],0.f);

#define LAYER30(wp, bp) \
        { _Pragma("unroll") for (int co=0;co<30;co++) c[co]=(bp)[co]; \
          _Pragma("unroll") for (int ci=0;ci<30;ci++){ float v=a[ci]; \
            _Pragma("unroll") for (int co=0;co<30;co++) c[co]=fmaf(v,(wp)[ci*30+co],c[co]); } \
          _Pragma("unroll") for (int co=0;co<30;co++) a[co]=fmaxf(c[co],0.f); }

        LAYER30(w1,b1);
        LAYER30(w2,b2);
        LAYER30(w3,b3);
#undef LAYER30

        int py = tid/13, px = tid - py*13;
        int L = (py+2)*17 + (px+2);
        #pragma unroll
        for (int ci=0;ci<30;ci++)
            img[L*32 + ((((ci>>3) + L)&3)<<3) + (ci&7)] = (_Float16)a[ci];
    }

    // per-M-tile pixel bases (layer/kt-invariant)
    int pL[3]; bool mv[3];
    #pragma unroll
    for (int mi=0; mi<3; mi++){
        int Mt = wave + mi*4;
        mv[mi] = (Mt < 11);
        int p = Mt*16 + m16;
        int py = p/13, px = p - py*13;
        pL[mi] = py*17 + px;
    }

    // ---- Phases 1-4: 5x5 conv + ReLU, 1-term f16 MFMA, in-LDS chaining ----
    #pragma unroll 1
    for (int layer=0; layer<4; layer++){
        const float* bias = (layer==0)?cb0:(layer==1)?cb1:(layer==2)?cb2:cb3;
        const _Float16* wh = cw + (size_t)layer*25600;

        __syncthreads();   // chain writes (L0) / writeback (L1-3) visible

        float bb[2];
        #pragma unroll
        for (int nt=0; nt<2; nt++){
            int co = nt*16 + m16;
            bb[nt] = (co < 30) ? bias[co] : 0.f;
        }
        facc acc[3][2];
        #pragma unroll
        for (int mi=0; mi<3; mi++)
            #pragma unroll
            for (int nt=0; nt<2; nt++)
                acc[mi][nt] = (facc){bb[nt], bb[nt], bb[nt], bb[nt]};

        #pragma unroll 1
        for (int kt=0; kt<25; kt++){
            int dy = kt/5, dx = kt - dy*5;
            int Ld = dy*17 + dx;
            hfrag ah[3];
            #pragma unroll
            for (int mi=0; mi<3; mi++){
                if (mv[mi]){
                    int L = pL[mi] + Ld;
                    int o = L*32 + (((quad + L)&3)<<3);
                    ah[mi] = *(const hfrag*)(img + o);
                }
            }
            const _Float16* whp = wh + (size_t)(kt*2)*512 + lane*8;
            hfrag wh0 = *(const hfrag*)(whp);
            hfrag wh1 = *(const hfrag*)(whp + 512);
            #pragma unroll
            for (int mi=0; mi<3; mi++){
                if (mv[mi]){
                    acc[mi][0] = __builtin_amdgcn_mfma_f32_16x16x32_f16(ah[mi], wh0, acc[mi][0],0,0,0);
                    acc[mi][1] = __builtin_amdgcn_mfma_f32_16x16x32_f16(ah[mi], wh1, acc[mi][1],0,0,0);
                }
            }
        }

        __syncthreads();   // all img reads of this layer done before overwrite

        if (layer < 3){
            // writeback ReLU(acc) into img (same swizzle as staging)
            #pragma unroll
            for (int mi=0; mi<3; mi++){
                if (mv[mi]){
                    int Mt = wave + mi*4;
                    #pragma unroll
                    for (int nt=0; nt<2; nt++){
                        int co = nt*16 + m16;
                        if (co < 30){
                            #pragma unroll
                            for (int i2=0; i2<4; i2++){
                                int p = Mt*16 + quad*4 + i2;
                                if (p < NPIX){
                                    float v = fmaxf(acc[mi][nt][i2], 0.f);
                                    int py = p/13, px = p - py*13;
                                    int L = (py+2)*17 + (px+2);
                                    img[L*32 + ((((co>>3) + L)&3)<<3) + (co&7)] = (_Float16)v;
                                }
                            }
                        }
                    }
                }
            }
        } else {
            // final layer: store f32 to global for the LSTM
            #pragma unroll
            for (int mi=0; mi<3; mi++){
                if (mv[mi]){
                    int Mt = wave + mi*4;
                    #pragma unroll
                    for (int nt=0; nt<2; nt++){
                        int co = nt*16 + m16;
                        if (co < 30){
                            #pragma unroll
                            for (int i2=0; i2<4; i2++){
                                int p = Mt*16 + quad*4 + i2;
                                if (p < NPIX)
                                    ip[(size_t)co*N_ROWS + p] = fmaxf(acc[mi][nt][i2], 0.f);
                            }
                        }
                    }
                }
            }
        }
    }
}

// ---------------------------------------------------------------------------
// Kernel 3: LSTM MFMA weight repack, f16 single. (unchanged)
// ---------------------------------------------------------------------------
__global__ __launch_bounds__(256) void repack_mfma_f16(
    const float* __restrict__ l1w, const float* __restrict__ l1b,
    const float* __restrict__ l2w, const float* __restrict__ l2b,
    _Float16* __restrict__ bw1, _Float16* __restrict__ bw2,
    float* __restrict__ pbias1, float* __restrict__ pbias2)
{
    const int S1 = 5*32*512;   // 81920
    const int S2 = 7*32*512;   // 114688
    int i = blockIdx.x*256 + threadIdx.x;
    if (i < S1){
        int fr = i >> 9, r = i & 511;
        int kt = fr >> 5, ct = fr & 31;
        int lane = r >> 3, j = r & 7;
        int k = kt*32 + ((lane>>4)<<3) + j;
        int n = lane & 15;
        int cell = ((ct>>2)<<4) + n, g = ct & 3;
        float w = (k<130 && cell<100) ? l1w[(size_t)k*400 + g*100 + cell] : 0.f;
        bw1[i] = (_Float16)w;
    } else if (i < S1 + S2){
        int ii = i - S1;
        int fr = ii >> 9, r = ii & 511;
        int kt = fr >> 5, ct = fr & 31;
        int lane = r >> 3, j = r & 7;
        int k = kt*32 + ((lane>>4)<<3) + j;
        int n = lane & 15;
        int cell = ((ct>>2)<<4) + n, g = ct & 3;
        float w = (k<200 && cell<100) ? l2w[(size_t)k*400 + g*100 + cell] : 0.f;
        bw2[ii] = (_Float16)w;
    } else if (i < S1+S2+512){
        int col = i - S1 - S2;
        int ct = col >> 4, n = col & 15;
        int cell = ((ct>>2)<<4) + n, g = ct & 3;
        pbias1[col] = (cell<100) ? l1b[g*100+cell] : 0.f;
    } else if (i < S1+S2+1024){
        int col = i - S1 - S2 - 512;
        int ct = col >> 4, n = col & 15;
        int cell = ((ct>>2)<<4) + n, g = ct & 3;
        pbias2[col] = (cell<100) ? l2b[g*100+cell] : 0.f;
    }
}

// ---------------------------------------------------------------------------
// Kernel 4: PERSISTENT 2-layer LSTM + projection, v12. (unchanged from R11:
// measured 593 us. unroll-1 FINAL -- unroll 2 spilled at R7 and R10.)
// ---------------------------------------------------------------------------
#define NKT1 5
#define NKT2 7
#define M_BLK 32
#define RSTR 40            // row stride in _Float16 (80 B)
#define KTSTR (32*RSTR)    // 1280 per kt-tile
__global__ __launch_bounds__(512, 4) void lstm_mfma11(
    const float* __restrict__ xall,   // [55][30][N]
    const _Float16* __restrict__ bw1, const _Float16* __restrict__ bw2,
    const float* __restrict__ pbias1, const float* __restrict__ pbias2,
    const float* __restrict__ we, const float* __restrict__ be,
    float* __restrict__ out)          // [N][55]
{
    // A matrices single f16, [kt][row(32)][k(32)+pad(8)]
    __shared__ __align__(16) _Float16 A1[NKT1*KTSTR];   // 12.8 KB
    __shared__ __align__(16) _Float16 A2[NKT2*KTSTR];   // 17.9 KB
    __shared__ float pbuf[8*M_BLK];                     // 1 KB

    const int tid  = threadIdx.x;
    const int w    = tid >> 6, lane = tid & 63;
    const int m16  = lane & 15, quad = lane >> 4;
    const int n0   = blockIdx.x * M_BLK;
    const int cell = w*16 + m16;          // wave w owns cell-tile w
    const bool cv  = (cell < 100);

    for (int i=tid; i<NKT1*KTSTR; i+=512) A1[i]=(_Float16)0.f;
    for (int i=tid; i<NKT2*KTSTR; i+=512) A2[i]=(_Float16)0.f;
    for (int i=tid; i<8*M_BLK; i+=512) pbuf[i]=0.f;   // seg 7 stays 0 forever

    float cs1[2][4] = {{0,0,0,0},{0,0,0,0}};
    float cs2[2][4] = {{0,0,0,0},{0,0,0,0}};
    float b1[4], b2[4];
    #pragma unroll
    for (int g=0; g<4; g++){
        b1[g] = pbias1[(w*4+g)*16 + m16];
        b2[g] = pbias2[(w*4+g)*16 + m16];
    }
    const float weC = cv ? we[cell] : 0.f;
    const float be0 = be[0];

    // weight fragment bases: ct = w*4+g; per kt advance 32*512 = 16384
    const _Float16* w1p = bw1 + ((size_t)(w*4)*64 + lane)*8;
    const _Float16* w2p = bw2 + ((size_t)(w*4)*64 + lane)*8;

    const int sk = tid >> 3, sq = tid & 7;   // staging role (tid<240)

    __syncthreads();   // zero-init visible

    // stage x(0): column sk (k<30), rows sq*4..sq*4+3 (kt=0 tile)
    if (tid < 240){
        float4 v = *(const float4*)(xall + (size_t)sk*N_ROWS + n0 + sq*4);
        A1[(sq*4+0)*RSTR + sk] = (_Float16)v.x;
        A1[(sq*4+1)*RSTR + sk] = (_Float16)v.y;
        A1[(sq*4+2)*RSTR + sk] = (_Float16)v.z;
        A1[(sq*4+3)*RSTR + sk] = (_Float16)v.w;
    }
    __syncthreads();

    facc acc[2][4];   // [mt][g]

// 1-term f16 GEMM; per kt: 4 W loads, 2 A ds_reads, 8 MFMA. unroll 1 --
// FINAL (unroll 2 spilled at R7 and R10; knob retired).
#define GEMM(W0, NKT, AH, BI) \
    { _Pragma("unroll") \
      for (int mt=0; mt<2; mt++) \
        _Pragma("unroll") \
        for (int g=0; g<4; g++){ float bb=(BI)[g]; acc[mt][g]=(facc){bb,bb,bb,bb}; } \
      _Pragma("unroll 1") \
      for (int kt=0; kt<(NKT); kt++){ \
        hfrag ah[2]; \
        _Pragma("unroll") \
        for (int mt=0; mt<2; mt++){ \
            int off = kt*KTSTR + (mt*16+m16)*RSTR + (quad<<3); \
            ah[mt] = *(const hfrag*)((AH) + off); } \
        const _Float16* whp = (W0) + (size_t)kt*16384; \
        hfrag wh[4]; \
        _Pragma("unroll") \
        for (int g=0; g<4; g++) wh[g] = *(const hfrag*)(whp + (size_t)g*512); \
        _Pragma("unroll") \
        for (int g=0; g<4; g++){ \
            acc[0][g]=__builtin_amdgcn_mfma_f32_16x16x32_f16(ah[0],wh[g],acc[0][g],0,0,0); \
            acc[1][g]=__builtin_amdgcn_mfma_f32_16x16x32_f16(ah[1],wh[g],acc[1][g],0,0,0); } \
      } }

    for (int t=0; t<T_SEQ; t++){
        // prefetch x(t+1); latency hidden under GEMM1
        float4 xn;
        if (t+1 < T_SEQ && tid < 240)
            xn = *(const float4*)(xall + ((size_t)(t+1)*30+sk)*N_ROWS + n0 + sq*4);

        GEMM(w1p, NKT1, A1, b1);                           // layer 1
        __syncthreads();                                   // B1

        // EPI1: h1 -> A1 (k=30+cell) and A2 (k=cell).
        // cv guards the WHOLE epilogue: wave 7 takes execz, zero VALU.
        if (cv){
            #pragma unroll
            for (int mt=0; mt<2; mt++){
                #pragma unroll
                for (int i2=0;i2<4;i2++){
                    float gi = fast_sig(acc[mt][0][i2]);
                    float gj = fast_tanh(acc[mt][1][i2]);
                    float gf = fast_sig(acc[mt][2][i2] + 1.0f);
                    float go = fast_sig(acc[mt][3][i2]);
                    float cn = gf*cs1[mt][i2] + gi*gj;
                    cs1[mt][i2] = cn;
                    float h = go*fast_tanh(cn);
                    int row = mt*16 + quad*4 + i2;
                    _Float16 hh = (_Float16)h;
                    int k1 = 30 + cell;
                    A1[(k1>>5)*KTSTR + row*RSTR + (k1&31)] = hh;
                    A2[(cell>>5)*KTSTR + row*RSTR + (cell&31)] = hh;
                }
            }
        }
        // stage x(t+1) into A1 (GEMM1(t) done reading; next read after B2)
        if (t+1 < T_SEQ && tid < 240){
            A1[(sq*4+0)*RSTR + sk] = (_Float16)xn.x;
            A1[(sq*4+1)*RSTR + sk] = (_Float16)xn.y;
            A1[(sq*4+2)*RSTR + sk] = (_Float16)xn.z;
            A1[(sq*4+3)*RSTR + sk] = (_Float16)xn.w;
        }
        __syncthreads();                                   // B2

        GEMM(w2p, NKT2, A2, b2);                           // layer 2
        __syncthreads();                                   // B3

        // EPI2: h2 -> A2 (k=100+cell) + in-register projection partial.
        // Wave 7 skips everything (pbuf seg 7 pre-zeroed).
        if (w < 7){
            float pp[2][4] = {{0,0,0,0},{0,0,0,0}};
            if (cv){
                #pragma unroll
                for (int mt=0; mt<2; mt++){
                    #pragma unroll
                    for (int i2=0;i2<4;i2++){
                        float gi = fast_sig(acc[mt][0][i2]);
                        float gj = fast_tanh(acc[mt][1][i2]);
                        float gf = fast_sig(acc[mt][2][i2] + 1.0f);
                        float go = fast_sig(acc[mt][3][i2]);
                        float cn = gf*cs2[mt][i2] + gi*gj;
                        cs2[mt][i2] = cn;
                        float h = go*fast_tanh(cn);
                        pp[mt][i2] = h*weC;
                        int row = mt*16 + quad*4 + i2;
                        int k1 = 100 + cell;
                        A2[(k1>>5)*KTSTR + row*RSTR + (k1&31)] = (_Float16)h;
                    }
                }
            }
            // reduce over the 16 cells (m16 lanes) of this wave
            #pragma unroll
            for (int mt=0; mt<2; mt++){
                #pragma unroll
                for (int i2=0;i2<4;i2++){
                    float p = pp[mt][i2];
                    p += __shfl_xor(p, 1);
                    p += __shfl_xor(p, 2);
                    p += __shfl_xor(p, 4);
                    p += __shfl_xor(p, 8);
                    pp[mt][i2] = p;
                }
            }
            if (m16 == 0){
                #pragma unroll
                for (int mt=0; mt<2; mt++)
                    #pragma unroll
                    for (int i2=0;i2<4;i2++)
                        pbuf[w*M_BLK + mt*16 + quad*4 + i2] = pp[mt][i2];
            }
        }
        __syncthreads();                                   // B4

        if (tid < M_BLK){
            float s = be0;
            #pragma unroll
            for (int ww=0; ww<8; ww++) s += pbuf[ww*M_BLK + tid];
            out[(size_t)(n0+tid)*T_SEQ + t] = s;
        }
    }
#undef GEMM
}

// ---------------------------------------------------------------------------
extern "C" void kernel_launch(void* const* d_in, const int* in_sizes, int n_in,
                              void* d_out, int out_size, void* d_ws, size_t ws_size,
                              hipStream_t stream)
{
    const float* x    = (const float*)d_in[0];
    const float* w10  = (const float*)d_in[1];  const float* b10 = (const float*)d_in[2];
    const float* w11  = (const float*)d_in[3];  const float* b11 = (const float*)d_in[4];
    const float* w12  = (const float*)d_in[5];  const float* b12 = (const float*)d_in[6];
    const float* w13  = (const float*)d_in[7];  const float* b13 = (const float*)d_in[8];
    const float* w20  = (const float*)d_in[9];  const float* b20 = (const float*)d_in[10];
    const float* w21  = (const float*)d_in[11]; const float* b21 = (const float*)d_in[12];
    const float* w22  = (const float*)d_in[13]; const float* b22 = (const float*)d_in[14];
    const float* w23  = (const float*)d_in[15]; const float* b23 = (const float*)d_in[16];
    const float* l1w  = (const float*)d_in[17]; const float* l1b = (const float*)d_in[18];
    const float* l2w  = (const float*)d_in[19]; const float* l2b = (const float*)d_in[20];
    const float* we   = (const float*)d_in[21]; const float* be  = (const float*)d_in[22];
    float* out = (float*)d_out;

    // workspace layout preserved (same footprint). Conv f16 pack (204.8 KB)
    // overlays the lstm pack region; consumed by conv_fused before
    // repack_mfma_f16 overwrites it (stream-serialized).
    const size_t NF = (size_t)30*N_ROWS;
    float* buf0 = (float*)d_ws;                       // [55][30][N] floats
    unsigned short* packbase = (unsigned short*)(buf0 + (size_t)T_SEQ*NF);
    _Float16* bw1 = (_Float16*)packbase;                        // 81920
    _Float16* bw2 = (_Float16*)(packbase + 2*(5*32*512));       // 114688
    float* pbias1 = (float*)(packbase + 2*(5*32*512) + 2*(7*32*512));
    float* pbias2 = pbias1 + 512;

    _Float16* cwf = (_Float16*)packbase;              // 4*25600 f16

    repack_conv_f16<<<(4*25600+255)/256, 256, 0, stream>>>(w20, w21, w22, w23, cwf);

    conv_fused<<<T_SEQ*64, 256, 0, stream>>>(
        x, w10,b10, w11,b11, w12,b12, w13,b13,
        cwf, b20, b21, b22, b23, buf0);

    const int REPACK_N = 5*32*512 + 7*32*512 + 1024;
    repack_mfma_f16<<<(REPACK_N+255)/256, 256, 0, stream>>>(
        l1w, l1b, l2w, l2b, bw1, bw2, pbias1, pbias2);

    lstm_mfma11<<<N_ROWS/M_BLK, 512, 0, stream>>>(buf0, bw1, bw2,
                                                  pbias1, pbias2, we, be, out);
}